// Round 1
// baseline (394.423 us; speedup 1.0000x reference)
//
#include <hip/hip_runtime.h>
#include <stdint.h>
#include <math.h>

#define Bn 64
#define Tn 512
#define Dn 1024
#define Ln 32
#define LOG2E 1.4426950408889634f
#define LN2f  0.6931471805599453f

// workspace float offsets
#define EMIS_OFF 0
#define AL_OFF (Bn * Tn * Ln)
#define LOGNORM_OFF (AL_OFF + Bn * Tn * Ln)
#define SCORE_OFF (LOGNORM_OFF + Bn)
#define CNT_OFF (SCORE_OFF + Bn)

// ---------------------------------------------------------------------------
// Kernel 1: emissions = x @ W + bias. 256 blocks x 256 threads. (unchanged)
// ---------------------------------------------------------------------------
#define BM 128
#define KB 32
#define XSS 132

__global__ __launch_bounds__(256) void gemm_emis(
    const float* __restrict__ x, const float* __restrict__ Wm,
    const float* __restrict__ bias, const int* __restrict__ seqlen,
    float* __restrict__ emis)
{
    int b  = blockIdx.x >> 2;
    int t0 = (blockIdx.x & 3) * BM;
    if (t0 >= seqlen[b]) return;

    __shared__ __align__(16) float xs[KB * XSS];   // transposed: xs[k][row]
    __shared__ __align__(16) float wsh[KB * Ln];   // wsh[k][col]

    int tid = threadIdx.x;
    int cg = tid & 7;       // cols 4cg..4cg+3
    int rg = tid >> 3;      // rows 4rg..4rg+3 (0..31)

    const float* xrow = x + (size_t)(b * Tn + t0) * Dn;

    float acc[4][4];
    #pragma unroll
    for (int z = 0; z < 4; z++)
        #pragma unroll
        for (int c = 0; c < 4; c++) acc[z][c] = 0.f;

    float4 xr[4]; float4 wr;
    #pragma unroll
    for (int u = 0; u < 4; u++) {
        int f = tid + 256 * u;
        xr[u] = *(const float4*)(xrow + (size_t)(f >> 3) * Dn + (f & 7) * 4);
    }
    wr = *(const float4*)(Wm + tid * 4);

    for (int k0 = 0; k0 < Dn; k0 += KB) {
        __syncthreads();
        #pragma unroll
        for (int u = 0; u < 4; u++) {
            int f = tid + 256 * u;
            int lrow = f >> 3, kk = f & 7;
            xs[(4 * kk + 0) * XSS + lrow] = xr[u].x;
            xs[(4 * kk + 1) * XSS + lrow] = xr[u].y;
            xs[(4 * kk + 2) * XSS + lrow] = xr[u].z;
            xs[(4 * kk + 3) * XSS + lrow] = xr[u].w;
        }
        *(float4*)(wsh + tid * 4) = wr;
        __syncthreads();

        int kn = k0 + KB;
        if (kn < Dn) {
            #pragma unroll
            for (int u = 0; u < 4; u++) {
                int f = tid + 256 * u;
                xr[u] = *(const float4*)(xrow + (size_t)(f >> 3) * Dn + kn + (f & 7) * 4);
            }
            wr = *(const float4*)(Wm + (size_t)kn * Ln + tid * 4);
        }

        #pragma unroll 8
        for (int k = 0; k < KB; k++) {
            float4 a = *(const float4*)(xs + k * XSS + 4 * rg);
            float4 w = *(const float4*)(wsh + k * Ln + 4 * cg);
            float av[4] = {a.x, a.y, a.z, a.w};
            float wv[4] = {w.x, w.y, w.z, w.w};
            #pragma unroll
            for (int z = 0; z < 4; z++)
                #pragma unroll
                for (int c = 0; c < 4; c++)
                    acc[z][c] = fmaf(av[z], wv[c], acc[z][c]);
        }
    }

    float4 bv = *(const float4*)(bias + 4 * cg);
    float bb[4] = {bv.x, bv.y, bv.z, bv.w};
    #pragma unroll
    for (int z = 0; z < 4; z++) {
        float4 o;
        o.x = acc[z][0] + bb[0];
        o.y = acc[z][1] + bb[1];
        o.z = acc[z][2] + bb[2];
        o.w = acc[z][3] + bb[3];
        *(float4*)(emis + (size_t)(b * Tn + t0 + 4 * rg + z) * Ln + 4 * cg) = o;
    }
}

// ---------------------------------------------------------------------------
// Kernel 2: the two sequential chains, each alone on its own CU.
// grid 128 x 64 threads: blockIdx>>6 == 0 -> Viterbi (streams alphas to
// workspace), == 1 -> log-norm (shifted-linear, pow2 renorm every 4).
// No barriers, no co-resident helper waves, dedicated DS pipe per chain.
// Emissions prefetched from L2 one step ahead (off the critical chain).
// ---------------------------------------------------------------------------
__global__ __launch_bounds__(64) void crf_scan(
    const float* __restrict__ emis, const float* __restrict__ trans,
    const int* __restrict__ seqlen, float* __restrict__ al_g,
    float* __restrict__ wsf)
{
    __shared__ __align__(16) float abuf[64];

    int lane = threadIdx.x;
    int j = lane & 31;
    int role = blockIdx.x >> 6;
    int b = blockIdx.x & 63;
    int slen = seqlen[b];
    const float* eb = emis + (size_t)b * Tn * Ln;

    if (role == 0) {
        // ---------------- Viterbi forward ----------------
        float tr[32];
        #pragma unroll
        for (int i = 0; i < 32; i++) tr[i] = trans[i * Ln + j];

        float av = eb[j];
        if (lane < 32) al_g[(size_t)b * Tn * Ln + j] = av;
        float emit = eb[Ln + j];           // e[1]; unused if slen==1

        for (int t = 1; t < slen; t++) {
            int tn2 = (t + 1 < slen) ? (t + 1) : (slen - 1);
            float emitn = eb[(size_t)tn2 * Ln + j];   // off-chain prefetch
            abuf[lane] = av;                           // ds_write (full wave)
            float4 A0 = *(const float4*)(abuf + 0);
            float4 A1 = *(const float4*)(abuf + 4);
            float4 A2 = *(const float4*)(abuf + 8);
            float4 A3 = *(const float4*)(abuf + 12);
            float4 A4 = *(const float4*)(abuf + 16);
            float4 A5 = *(const float4*)(abuf + 20);
            float4 A6 = *(const float4*)(abuf + 24);
            float4 A7 = *(const float4*)(abuf + 28);
            float vv[32];
            vv[0]=A0.x+tr[0];   vv[1]=A0.y+tr[1];   vv[2]=A0.z+tr[2];   vv[3]=A0.w+tr[3];
            vv[4]=A1.x+tr[4];   vv[5]=A1.y+tr[5];   vv[6]=A1.z+tr[6];   vv[7]=A1.w+tr[7];
            vv[8]=A2.x+tr[8];   vv[9]=A2.y+tr[9];   vv[10]=A2.z+tr[10]; vv[11]=A2.w+tr[11];
            vv[12]=A3.x+tr[12]; vv[13]=A3.y+tr[13]; vv[14]=A3.z+tr[14]; vv[15]=A3.w+tr[15];
            vv[16]=A4.x+tr[16]; vv[17]=A4.y+tr[17]; vv[18]=A4.z+tr[18]; vv[19]=A4.w+tr[19];
            vv[20]=A5.x+tr[20]; vv[21]=A5.y+tr[21]; vv[22]=A5.z+tr[22]; vv[23]=A5.w+tr[23];
            vv[24]=A6.x+tr[24]; vv[25]=A6.y+tr[25]; vv[26]=A6.z+tr[26]; vv[27]=A6.w+tr[27];
            vv[28]=A7.x+tr[28]; vv[29]=A7.y+tr[29]; vv[30]=A7.z+tr[30]; vv[31]=A7.w+tr[31];
            float u[11];
            #pragma unroll
            for (int g = 0; g < 10; g++)
                u[g] = fmaxf(fmaxf(vv[3*g], vv[3*g+1]), vv[3*g+2]);
            u[10] = fmaxf(vv[30], vv[31]);
            float w0 = fmaxf(fmaxf(u[0], u[1]), u[2]);
            float w1 = fmaxf(fmaxf(u[3], u[4]), u[5]);
            float w2 = fmaxf(fmaxf(u[6], u[7]), u[8]);
            float w3 = fmaxf(u[9], u[10]);
            av = fmaxf(fmaxf(w0, w1), fmaxf(w2, w3)) + emit;
            if (lane < 32) al_g[((size_t)b * Tn + t) * Ln + j] = av;  // off-chain
            emit = emitn;
        }
    } else {
        // ---------------- log-norm (shifted-linear) ----------------
        float e2[32];
        #pragma unroll
        for (int i = 0; i < 32; i++) e2[i] = exp2f(trans[i * Ln + j] * LOG2E);

        float a = exp2f(eb[j] * LOG2E);
        float eemit = exp2f(eb[Ln + j] * LOG2E);   // unused if slen==1
        int Eacc = 0;

        for (int t = 1; t < slen; t++) {
            int tn2 = (t + 1 < slen) ? (t + 1) : (slen - 1);
            float emitn = eb[(size_t)tn2 * Ln + j];   // off-chain prefetch
            abuf[lane] = a;                            // ds_write (full wave)
            float4 A0 = *(const float4*)(abuf + 0);
            float4 A1 = *(const float4*)(abuf + 4);
            float4 A2 = *(const float4*)(abuf + 8);
            float4 A3 = *(const float4*)(abuf + 12);
            float4 A4 = *(const float4*)(abuf + 16);
            float4 A5 = *(const float4*)(abuf + 20);
            float4 A6 = *(const float4*)(abuf + 24);
            float4 A7 = *(const float4*)(abuf + 28);
            float eemitn = exp2f(emitn * LOG2E);       // off-chain
            float s0, s1, s2, s3;
            s0 = A0.x * e2[0];  s1 = A0.y * e2[1];  s2 = A0.z * e2[2];  s3 = A0.w * e2[3];
            s0 = fmaf(A1.x, e2[4], s0);  s1 = fmaf(A1.y, e2[5], s1);
            s2 = fmaf(A1.z, e2[6], s2);  s3 = fmaf(A1.w, e2[7], s3);
            s0 = fmaf(A2.x, e2[8], s0);  s1 = fmaf(A2.y, e2[9], s1);
            s2 = fmaf(A2.z, e2[10], s2); s3 = fmaf(A2.w, e2[11], s3);
            s0 = fmaf(A3.x, e2[12], s0); s1 = fmaf(A3.y, e2[13], s1);
            s2 = fmaf(A3.z, e2[14], s2); s3 = fmaf(A3.w, e2[15], s3);
            s0 = fmaf(A4.x, e2[16], s0); s1 = fmaf(A4.y, e2[17], s1);
            s2 = fmaf(A4.z, e2[18], s2); s3 = fmaf(A4.w, e2[19], s3);
            s0 = fmaf(A5.x, e2[20], s0); s1 = fmaf(A5.y, e2[21], s1);
            s2 = fmaf(A5.z, e2[22], s2); s3 = fmaf(A5.w, e2[23], s3);
            s0 = fmaf(A6.x, e2[24], s0); s1 = fmaf(A6.y, e2[25], s1);
            s2 = fmaf(A6.z, e2[26], s2); s3 = fmaf(A6.w, e2[27], s3);
            s0 = fmaf(A7.x, e2[28], s0); s1 = fmaf(A7.y, e2[29], s1);
            s2 = fmaf(A7.z, e2[30], s2); s3 = fmaf(A7.w, e2[31], s3);
            float s = ((s0 + s1) + (s2 + s3)) * eemit;
            if ((t & 3) == 0) {   // pow2 renorm every 4 steps (range-safe)
                unsigned sb = (unsigned)__builtin_amdgcn_readfirstlane(__float_as_int(s));
                int e = (int)((sb >> 23) & 0xFFu) - 127;
                Eacc += e;
                a = ldexpf(s, -e);
            } else {
                a = s;
            }
            eemit = eemitn;
        }

        float ss = a;
        #pragma unroll
        for (int off = 16; off >= 1; off >>= 1) ss += __shfl_xor(ss, off);
        if (lane == 0)
            wsf[LOGNORM_OFF + b] = fmaf(log2f(ss) + (float)Eacc, LN2f, 0.f);
    }
}

// ---------------------------------------------------------------------------
// Kernel 3: decode. 64 blocks x 512 threads. Reads alpha history back,
// recomputes backpointers massively parallel (14 half-wave stripes),
// seq-score + last-tag argmax on wave0, segmented backtrace, counts.
// ---------------------------------------------------------------------------
__global__ __launch_bounds__(512) void crf_decode(
    const float* __restrict__ emis, const float* __restrict__ trans,
    const int* __restrict__ label, const int* __restrict__ seqlen,
    const float* __restrict__ al_g, float* __restrict__ out,
    float* __restrict__ wsf)
{
    __shared__ __align__(16) float al_s[Tn * Ln];   // 64 KB alpha history
    __shared__ __align__(16) float trs[Ln * Ln];    // 4 KB transitions
    __shared__ uint8_t bp[Tn * Ln];                 // 16 KB backpointers
    __shared__ uint8_t Fm[16 * 32];
    __shared__ int btag[16];
    __shared__ int s_last;
    __shared__ float credA[8], credB[8], credC[8];

    int tid = threadIdx.x;
    int b = blockIdx.x;
    int slen = seqlen[b];
    int wv = tid >> 6;
    int lane = tid & 63;
    int j = lane & 31;

    // stage alpha history + transitions; init bp to identity
    {
        const float4* src = (const float4*)(al_g + (size_t)b * Tn * Ln);
        int n4 = slen * (Ln / 4);
        for (int i4 = tid; i4 < n4; i4 += 512)
            ((float4*)al_s)[i4] = src[i4];
    }
    if (tid < 256) ((float4*)trs)[tid] = ((const float4*)trans)[tid];
    {
        uint32_t* bp32 = (uint32_t*)bp;
        for (int w = tid; w < Tn * Ln / 4; w += 512)
            bp32[w] = 0x03020100u + 0x04040404u * (uint32_t)(w & 7);
    }
    __syncthreads();

    if (wv == 0) {
        // ---------- sequence score ----------
        const int* lb = label + (size_t)b * Tn;
        const float* eg = emis + (size_t)b * Tn * Ln;
        float acc = 0.f;
        for (int t = lane; t < Tn; t += 64) {
            if (t < slen) {
                int lc = lb[t];
                acc += eg[(size_t)t * Ln + lc];
                if (t >= 1) acc += trs[lb[t - 1] * Ln + lc];
            }
        }
        #pragma unroll
        for (int off = 32; off >= 1; off >>= 1) acc += __shfl_xor(acc, off);
        if (lane == 0) wsf[SCORE_OFF + b] = acc;

        // ---------- last-tag argmax ----------
        float mm = al_s[(slen - 1) * Ln + j];
        int ai = j;
        #pragma unroll
        for (int off = 16; off >= 1; off >>= 1) {
            float om = __shfl_xor(mm, off);
            int   oi = __shfl_xor(ai, off);
            if (om > mm || (om == mm && oi < ai)) { mm = om; ai = oi; }
        }
        if (lane == 0) s_last = ai;
    } else {
        // ---------- bp recompute, 14 half-wave stripes ----------
        float tr[32];
        #pragma unroll
        for (int i = 0; i < 32; i++) tr[i] = trs[i * Ln + j];
        int stripe = (wv - 1) * 2 + (lane >> 5);   // 0..13
        for (int t = 1 + stripe; t < slen; t += 14) {
            const float* ar = al_s + (t - 1) * Ln;
            float vv[32];
            #pragma unroll
            for (int i = 0; i < 32; i += 4) {
                float4 a4 = *(const float4*)(ar + i);
                vv[i]     = a4.x + tr[i];
                vv[i + 1] = a4.y + tr[i + 1];
                vv[i + 2] = a4.z + tr[i + 2];
                vv[i + 3] = a4.w + tr[i + 3];
            }
            float mv[16]; int mi[16];
            #pragma unroll
            for (int i = 0; i < 16; i++) {
                bool g = vv[2*i+1] > vv[2*i];
                mv[i] = g ? vv[2*i+1] : vv[2*i];
                mi[i] = g ? (2*i+1) : (2*i);
            }
            #pragma unroll
            for (int i = 0; i < 8; i++) {
                bool g = mv[2*i+1] > mv[2*i];
                mv[i] = g ? mv[2*i+1] : mv[2*i];
                mi[i] = g ? mi[2*i+1] : mi[2*i];
            }
            #pragma unroll
            for (int i = 0; i < 4; i++) {
                bool g = mv[2*i+1] > mv[2*i];
                mv[i] = g ? mv[2*i+1] : mv[2*i];
                mi[i] = g ? mi[2*i+1] : mi[2*i];
            }
            #pragma unroll
            for (int i = 0; i < 2; i++) {
                bool g = mv[2*i+1] > mv[2*i];
                mv[i] = g ? mv[2*i+1] : mv[2*i];
                mi[i] = g ? mi[2*i+1] : mi[2*i];
            }
            bp[t * Ln + j] = (uint8_t)mi[0];
        }
    }
    __syncthreads();

    // ---------------- segmented parallel backtrace ----------------
    int sseg = tid >> 5, ent = tid & 31;
    {
        int y = ent;
        for (int p = 32 * sseg + 31; p >= 32 * sseg; p--) y = bp[p * Ln + y];
        Fm[sseg * 32 + ent] = (uint8_t)y;
    }
    __syncthreads();
    if (tid == 0) {
        int y = s_last;
        btag[15] = y;
        for (int ss = 15; ss >= 1; ss--) { y = Fm[ss * 32 + y]; btag[ss - 1] = y; }
    }
    __syncthreads();
    int q = tid;
    int y = btag[sseg];
    for (int p = 32 * sseg + 31; p >= q + 1; p--) y = bp[p * Ln + y];
    out[1 + (size_t)b * Tn + q] = (float)y;

    int lbl = label[(size_t)b * Tn + q];
    float tpf = (lbl > 0 && y == lbl) ? 1.f : 0.f;
    float tnf = (lbl > 0 && y != lbl) ? 1.f : 0.f;
    float fpf = (q < slen && lbl == 0 && y > 0) ? 1.f : 0.f;
    #pragma unroll
    for (int off = 32; off >= 1; off >>= 1) {
        tpf += __shfl_xor(tpf, off);
        tnf += __shfl_xor(tnf, off);
        fpf += __shfl_xor(fpf, off);
    }
    if (lane == 0) { credA[wv] = tpf; credB[wv] = tnf; credC[wv] = fpf; }
    __syncthreads();
    if (tid == 0) {
        float aa = 0.f, bb2 = 0.f, cc2 = 0.f;
        #pragma unroll
        for (int w = 0; w < 8; w++) { aa += credA[w]; bb2 += credB[w]; cc2 += credC[w]; }
        wsf[CNT_OFF + b] = aa;
        wsf[CNT_OFF + Bn + b] = bb2;
        wsf[CNT_OFF + 2 * Bn + b] = cc2;
    }
}

// ---------------------------------------------------------------------------
// Kernel 4: final scalar reductions
// ---------------------------------------------------------------------------
__global__ __launch_bounds__(64) void crf_final(const float* __restrict__ wsf,
                                                float* __restrict__ out)
{
    int lane = threadIdx.x;
    float nll = wsf[LOGNORM_OFF + lane] - wsf[SCORE_OFF + lane];
    float tp = wsf[CNT_OFF + lane];
    float tn = wsf[CNT_OFF + Bn + lane];
    float fp = wsf[CNT_OFF + 2 * Bn + lane];
    #pragma unroll
    for (int off = 32; off >= 1; off >>= 1) {
        nll += __shfl_xor(nll, off);
        tp  += __shfl_xor(tp, off);
        tn  += __shfl_xor(tn, off);
        fp  += __shfl_xor(fp, off);
    }
    if (lane == 0) {
        out[0] = nll * (1.f / 64.f);
        out[1 + Bn * Tn + 0] = tp;
        out[1 + Bn * Tn + 1] = tn;
        out[1 + Bn * Tn + 2] = fp;
    }
}

extern "C" void kernel_launch(void* const* d_in, const int* in_sizes, int n_in,
                              void* d_out, int out_size, void* d_ws, size_t ws_size,
                              hipStream_t stream) {
    const float* x     = (const float*)d_in[0];
    const float* W     = (const float*)d_in[1];
    const float* bias  = (const float*)d_in[2];
    const float* trans = (const float*)d_in[3];
    const int* label   = (const int*)d_in[4];
    const int* seqlen  = (const int*)d_in[5];
    float* out = (float*)d_out;
    float* wsf = (float*)d_ws;

    gemm_emis<<<dim3(Bn * (Tn / BM)), dim3(256), 0, stream>>>(x, W, bias, seqlen, wsf + EMIS_OFF);
    crf_scan<<<dim3(2 * Bn), dim3(64), 0, stream>>>(wsf + EMIS_OFF, trans, seqlen, wsf + AL_OFF, wsf);
    crf_decode<<<dim3(Bn), dim3(512), 0, stream>>>(wsf + EMIS_OFF, trans, label, seqlen, wsf + AL_OFF, out, wsf);
    crf_final<<<dim3(1), dim3(64), 0, stream>>>(wsf, out);
}

// Round 2
// 294.987 us; speedup vs baseline: 1.3371x; 1.3371x over previous
//
#include <hip/hip_runtime.h>
#include <stdint.h>
#include <math.h>

#define Bn 64
#define Tn 512
#define Dn 1024
#define Ln 32
#define LOG2E 1.4426950408889634f
#define LN2f  0.6931471805599453f

// workspace float offsets
#define EMIS_OFF 0
#define LOGNORM_OFF (Bn * Tn * Ln)
#define SCORE_OFF (LOGNORM_OFF + Bn)
#define CNT_OFF (SCORE_OFF + Bn)

// max3 helper: compiler fuses fmaxf(fmaxf(a,b),c) -> v_max3_f32
#define MAX3(a,b,c) fmaxf(fmaxf((a),(b)),(c))

// cross-half exchange: after swap, {x,y} hold {own, other} in some order on
// every lane, so a commutative combine needs no lane-select.
__device__ __forceinline__ void half_swap(float p, float& x, float& y) {
    x = p; y = p;
    asm volatile("v_permlane32_swap_b32 %0, %1" : "+v"(x), "+v"(y));
}

// ---------------------------------------------------------------------------
// Kernel 1: emissions = x @ W + bias. 256 blocks x 256 threads. (unchanged)
// ---------------------------------------------------------------------------
#define BM 128
#define KB 32
#define XSS 132

__global__ __launch_bounds__(256) void gemm_emis(
    const float* __restrict__ x, const float* __restrict__ Wm,
    const float* __restrict__ bias, const int* __restrict__ seqlen,
    float* __restrict__ emis)
{
    int b  = blockIdx.x >> 2;
    int t0 = (blockIdx.x & 3) * BM;
    if (t0 >= seqlen[b]) return;

    __shared__ __align__(16) float xs[KB * XSS];   // transposed: xs[k][row]
    __shared__ __align__(16) float wsh[KB * Ln];   // wsh[k][col]

    int tid = threadIdx.x;
    int cg = tid & 7;       // cols 4cg..4cg+3
    int rg = tid >> 3;      // rows 4rg..4rg+3 (0..31)

    const float* xrow = x + (size_t)(b * Tn + t0) * Dn;

    float acc[4][4];
    #pragma unroll
    for (int z = 0; z < 4; z++)
        #pragma unroll
        for (int c = 0; c < 4; c++) acc[z][c] = 0.f;

    // prologue: prefetch chunk 0 into registers
    float4 xr[4]; float4 wr;
    #pragma unroll
    for (int u = 0; u < 4; u++) {
        int f = tid + 256 * u;
        xr[u] = *(const float4*)(xrow + (size_t)(f >> 3) * Dn + (f & 7) * 4);
    }
    wr = *(const float4*)(Wm + tid * 4);

    for (int k0 = 0; k0 < Dn; k0 += KB) {
        __syncthreads();
        #pragma unroll
        for (int u = 0; u < 4; u++) {
            int f = tid + 256 * u;
            int lrow = f >> 3, kk = f & 7;
            xs[(4 * kk + 0) * XSS + lrow] = xr[u].x;
            xs[(4 * kk + 1) * XSS + lrow] = xr[u].y;
            xs[(4 * kk + 2) * XSS + lrow] = xr[u].z;
            xs[(4 * kk + 3) * XSS + lrow] = xr[u].w;
        }
        *(float4*)(wsh + tid * 4) = wr;
        __syncthreads();

        int kn = k0 + KB;
        if (kn < Dn) {
            #pragma unroll
            for (int u = 0; u < 4; u++) {
                int f = tid + 256 * u;
                xr[u] = *(const float4*)(xrow + (size_t)(f >> 3) * Dn + kn + (f & 7) * 4);
            }
            wr = *(const float4*)(Wm + (size_t)kn * Ln + tid * 4);
        }

        #pragma unroll 8
        for (int k = 0; k < KB; k++) {
            float4 a = *(const float4*)(xs + k * XSS + 4 * rg);
            float4 w = *(const float4*)(wsh + k * Ln + 4 * cg);
            float av[4] = {a.x, a.y, a.z, a.w};
            float wv[4] = {w.x, w.y, w.z, w.w};
            #pragma unroll
            for (int z = 0; z < 4; z++)
                #pragma unroll
                for (int c = 0; c < 4; c++)
                    acc[z][c] = fmaf(av[z], wv[c], acc[z][c]);
        }
    }

    float4 bv = *(const float4*)(bias + 4 * cg);
    float bb[4] = {bv.x, bv.y, bv.z, bv.w};
    #pragma unroll
    for (int z = 0; z < 4; z++) {
        float4 o;
        o.x = acc[z][0] + bb[0];
        o.y = acc[z][1] + bb[1];
        o.z = acc[z][2] + bb[2];
        o.w = acc[z][3] + bb[3];
        *(float4*)(emis + (size_t)(b * Tn + t0 + 4 * rg + z) * Ln + 4 * cg) = o;
    }
}

// ---------------------------------------------------------------------------
// Kernel 2: per-batch CRF. grid 64 x 512. Chunked pipeline (CH=64):
//   wave0 = Viterbi forward, wave1 = log-norm, waves2-7 = seq-score (c=0)
//   then bp recompute for chunk c-1.
// R2 change: scan chains split the reduction axis across wave halves —
// lanes 0-31 reduce i=0..15, lanes 32-63 reduce i=16..31, combined with one
// v_permlane32_swap_b32 (VALU pipe). Halves broadcast ds_reads (8->4 b128)
// and VALU work; all-lane abuf/al writes drop the exec-mask toggles.
// Viterbi alpha values are bit-identical to the unsplit form (max exact,
// per-term add order unchanged), so helper bp recompute is unaffected.
// ---------------------------------------------------------------------------
#define CH 64

__global__ __launch_bounds__(512) void crf_forward(
    const float* __restrict__ emis, const float* __restrict__ trans,
    const int* __restrict__ label, const int* __restrict__ seqlen,
    float* __restrict__ out, float* __restrict__ wsf)
{
    __shared__ __align__(16) float es[Tn * Ln];   // 64 KB emissions
    __shared__ __align__(16) float al[Tn * Ln];   // 64 KB alphas
    __shared__ __align__(16) float trs[Ln * Ln];  // 4 KB transitions
    __shared__ __align__(16) float abuf[64];      // viterbi broadcast buffer
    __shared__ __align__(16) float lbuf[64];      // LSE broadcast buffer
    __shared__ uint8_t bp[Tn * Ln];               // 16 KB backpointers
    __shared__ uint8_t Fm[16 * 32];
    __shared__ int btag[16];
    __shared__ int s_last;
    __shared__ float credA[8], credB[8], credC[8];

    int tid = threadIdx.x;
    int b = blockIdx.x;
    int slen = seqlen[b];
    int wv = tid >> 6;
    int lane = tid & 63;
    int j = lane & 31;
    int half = lane >> 5;          // 0: reduce i=0..15, 1: reduce i=16..31

    const float* eb = emis + (size_t)b * Tn * Ln;

    {
        int n4 = slen * (Ln / 4);
        for (int i4 = tid; i4 < n4; i4 += 512)
            ((float4*)es)[i4] = ((const float4*)eb)[i4];
    }
    if (tid < 256) ((float4*)trs)[tid] = ((const float4*)trans)[tid];
    {
        uint32_t* bp32 = (uint32_t*)bp;
        for (int w = tid; w < Tn * Ln / 4; w += 512)
            bp32[w] = 0x03020100u + 0x04040404u * (uint32_t)(w & 7);
    }
    __syncthreads();

    float av = 0.f, emit = 0.f;            // viterbi
    float a = 0.f, eemit = 0.f;            // LSE
    int   Eacc = 0;
    float tr[32];
    float e2[16];

    // half-dependent broadcast base: lower half reads abuf[0..15] (= av[0..15]),
    // upper half reads abuf[48..63] (its own duplicate of av[16..31]).
    const int hoff = half ? 48 : 0;

    if (wv == 0) {
        #pragma unroll
        for (int i = 0; i < 16; i++) tr[i] = trs[(16 * half + i) * Ln + j];
        av = es[j];
        al[j] = av;                        // both halves write same value
        emit = es[Ln + j];
    } else if (wv == 1) {
        #pragma unroll
        for (int i = 0; i < 16; i++) e2[i] = exp2f(trs[(16 * half + i) * Ln + j] * LOG2E);
        a = exp2f(es[j] * LOG2E);
        eemit = exp2f(es[Ln + j] * LOG2E);
    } else {
        #pragma unroll
        for (int i = 0; i < 32; i++) tr[i] = trs[i * Ln + j];
    }

    for (int c = 0; c < Tn / CH; c++) {
        int tb = (c == 0) ? 1 : c * CH;
        int te = (c + 1) * CH; if (te > slen) te = slen;

        if (wv == 0) {
            // ---------- Viterbi: half-split broadcast + max3 tree ----------
            for (int t = tb; t < te; t++) {
                int tnx = (t + 1 < slen) ? (t + 1) : (slen - 1);
                float emitn = es[tnx * Ln + j];        // independent ds_read
                abuf[lane] = av;                       // all 64 lanes
                float4 A0 = *(const float4*)(abuf + hoff + 0);
                float4 A1 = *(const float4*)(abuf + hoff + 4);
                float4 A2 = *(const float4*)(abuf + hoff + 8);
                float4 A3 = *(const float4*)(abuf + hoff + 12);
                float vv[16];
                vv[0]=A0.x+tr[0];   vv[1]=A0.y+tr[1];   vv[2]=A0.z+tr[2];   vv[3]=A0.w+tr[3];
                vv[4]=A1.x+tr[4];   vv[5]=A1.y+tr[5];   vv[6]=A1.z+tr[6];   vv[7]=A1.w+tr[7];
                vv[8]=A2.x+tr[8];   vv[9]=A2.y+tr[9];   vv[10]=A2.z+tr[10]; vv[11]=A2.w+tr[11];
                vv[12]=A3.x+tr[12]; vv[13]=A3.y+tr[13]; vv[14]=A3.z+tr[14]; vv[15]=A3.w+tr[15];
                float g0 = MAX3(vv[0],  vv[1],  vv[2]);
                float g1 = MAX3(vv[3],  vv[4],  vv[5]);
                float g2 = MAX3(vv[6],  vv[7],  vv[8]);
                float g3 = MAX3(vv[9],  vv[10], vv[11]);
                float g4 = MAX3(vv[12], vv[13], vv[14]);
                float h0 = MAX3(g0, g1, g2);
                float h1 = MAX3(g3, g4, vv[15]);
                float p = fmaxf(h0, h1);
                float xx, yy;
                half_swap(p, xx, yy);                  // cross-half exchange
                av = fmaxf(xx, yy) + emit;
                al[t * Ln + j] = av;                   // both halves, same value
                emit = emitn;
            }
        } else if (wv == 1) {
            // ---------- LSE: half-split broadcast, shifted-linear ----------
            for (int t = tb; t < te; t++) {
                int tnx = (t + 1 < slen) ? (t + 1) : (slen - 1);
                float emitn = es[tnx * Ln + j];
                lbuf[lane] = a;                        // all 64 lanes
                float4 A0 = *(const float4*)(lbuf + hoff + 0);
                float4 A1 = *(const float4*)(lbuf + hoff + 4);
                float4 A2 = *(const float4*)(lbuf + hoff + 8);
                float4 A3 = *(const float4*)(lbuf + hoff + 12);
                float eemitn = exp2f(emitn * LOG2E);   // off-chain
                float s0, s1, s2, s3;
                s0 = A0.x * e2[0];  s1 = A0.y * e2[1];  s2 = A0.z * e2[2];  s3 = A0.w * e2[3];
                s0 = fmaf(A1.x, e2[4],  s0); s1 = fmaf(A1.y, e2[5],  s1);
                s2 = fmaf(A1.z, e2[6],  s2); s3 = fmaf(A1.w, e2[7],  s3);
                s0 = fmaf(A2.x, e2[8],  s0); s1 = fmaf(A2.y, e2[9],  s1);
                s2 = fmaf(A2.z, e2[10], s2); s3 = fmaf(A2.w, e2[11], s3);
                s0 = fmaf(A3.x, e2[12], s0); s1 = fmaf(A3.y, e2[13], s1);
                s2 = fmaf(A3.z, e2[14], s2); s3 = fmaf(A3.w, e2[15], s3);
                float p = (s0 + s1) + (s2 + s3);
                float xx, yy;
                half_swap(p, xx, yy);                  // cross-half exchange
                float s = (xx + yy) * eemit;
                if ((t & 3) == 0) {   // pow2 renorm every 4 steps (range-safe)
                    unsigned sb = (unsigned)__builtin_amdgcn_readfirstlane(__float_as_int(s));
                    int e = (int)((sb >> 23) & 0xFFu) - 127;
                    Eacc += e;
                    a = ldexpf(s, -e);
                } else {
                    a = s;
                }
                eemit = eemitn;
            }
        } else if (c == 0) {
            if (wv == 2) {
                const int* lb = label + (size_t)b * Tn;
                float acc = 0.f;
                for (int t = lane; t < Tn; t += 64) {
                    if (t < slen) {
                        int lc = lb[t];
                        acc += es[t * Ln + lc];
                        if (t >= 1) acc += trs[lb[t - 1] * Ln + lc];
                    }
                }
                #pragma unroll
                for (int off = 32; off >= 1; off >>= 1) acc += __shfl_xor(acc, off);
                if (lane == 0) wsf[SCORE_OFF + b] = acc;
            }
        } else {
            // ---------- bp recompute for chunk c-1 (12 stripes) ----------
            int stripe = (wv - 2) * 2 + (lane >> 5);
            int pb = ((c - 1) == 0) ? 1 : (c - 1) * CH;
            int pe = c * CH; if (pe > slen) pe = slen;
            for (int t = pb + stripe; t < pe; t += 12) {
                const float* ar = al + (t - 1) * Ln;
                float vv[32];
                #pragma unroll
                for (int i = 0; i < 32; i += 4) {
                    float4 a4 = *(const float4*)(ar + i);
                    vv[i]     = a4.x + tr[i];
                    vv[i + 1] = a4.y + tr[i + 1];
                    vv[i + 2] = a4.z + tr[i + 2];
                    vv[i + 3] = a4.w + tr[i + 3];
                }
                float mv[16]; int mi[16];
                #pragma unroll
                for (int i = 0; i < 16; i++) {
                    bool g = vv[2*i+1] > vv[2*i];
                    mv[i] = g ? vv[2*i+1] : vv[2*i];
                    mi[i] = g ? (2*i+1) : (2*i);
                }
                #pragma unroll
                for (int i = 0; i < 8; i++) {
                    bool g = mv[2*i+1] > mv[2*i];
                    mv[i] = g ? mv[2*i+1] : mv[2*i];
                    mi[i] = g ? mi[2*i+1] : mi[2*i];
                }
                #pragma unroll
                for (int i = 0; i < 4; i++) {
                    bool g = mv[2*i+1] > mv[2*i];
                    mv[i] = g ? mv[2*i+1] : mv[2*i];
                    mi[i] = g ? mi[2*i+1] : mi[2*i];
                }
                #pragma unroll
                for (int i = 0; i < 2; i++) {
                    bool g = mv[2*i+1] > mv[2*i];
                    mv[i] = g ? mv[2*i+1] : mv[2*i];
                    mi[i] = g ? mi[2*i+1] : mi[2*i];
                }
                bp[t * Ln + j] = (uint8_t)mi[0];
            }
        }
        __syncthreads();
    }

    // tail
    if (wv == 0) {
        float mm = av; int ai = j;
        #pragma unroll
        for (int off = 16; off >= 1; off >>= 1) {
            float om = __shfl_xor(mm, off);
            int   oi = __shfl_xor(ai, off);
            if (om > mm || (om == mm && oi < ai)) { mm = om; ai = oi; }
        }
        if (lane == 0) s_last = ai;
    } else if (wv == 1) {
        float ss = a;
        #pragma unroll
        for (int off = 16; off >= 1; off >>= 1) ss += __shfl_xor(ss, off);
        if (lane == 0)
            wsf[LOGNORM_OFF + b] = fmaf(log2f(ss) + (float)Eacc, LN2f, 0.f);
    } else {
        int stripe = (wv - 2) * 2 + (lane >> 5);
        int cc = Tn / CH - 1;
        int pb = cc * CH;
        int pe = Tn; if (pe > slen) pe = slen;
        for (int t = pb + stripe; t < pe; t += 12) {
            const float* ar = al + (t - 1) * Ln;
            float vv[32];
            #pragma unroll
            for (int i = 0; i < 32; i += 4) {
                float4 a4 = *(const float4*)(ar + i);
                vv[i]     = a4.x + tr[i];
                vv[i + 1] = a4.y + tr[i + 1];
                vv[i + 2] = a4.z + tr[i + 2];
                vv[i + 3] = a4.w + tr[i + 3];
            }
            float mv[16]; int mi[16];
            #pragma unroll
            for (int i = 0; i < 16; i++) {
                bool g = vv[2*i+1] > vv[2*i];
                mv[i] = g ? vv[2*i+1] : vv[2*i];
                mi[i] = g ? (2*i+1) : (2*i);
            }
            #pragma unroll
            for (int i = 0; i < 8; i++) {
                bool g = mv[2*i+1] > mv[2*i];
                mv[i] = g ? mv[2*i+1] : mv[2*i];
                mi[i] = g ? mi[2*i+1] : mi[2*i];
            }
            #pragma unroll
            for (int i = 0; i < 4; i++) {
                bool g = mv[2*i+1] > mv[2*i];
                mv[i] = g ? mv[2*i+1] : mv[2*i];
                mi[i] = g ? mi[2*i+1] : mi[2*i];
            }
            #pragma unroll
            for (int i = 0; i < 2; i++) {
                bool g = mv[2*i+1] > mv[2*i];
                mv[i] = g ? mv[2*i+1] : mv[2*i];
                mi[i] = g ? mi[2*i+1] : mi[2*i];
            }
            bp[t * Ln + j] = (uint8_t)mi[0];
        }
    }
    __syncthreads();

    // ---------------- segmented parallel backtrace ----------------
    int sseg = tid >> 5, ent = tid & 31;
    {
        int y = ent;
        for (int p = 32 * sseg + 31; p >= 32 * sseg; p--) y = bp[p * Ln + y];
        Fm[sseg * 32 + ent] = (uint8_t)y;
    }
    __syncthreads();
    if (tid == 0) {
        int y = s_last;
        btag[15] = y;
        for (int ss = 15; ss >= 1; ss--) { y = Fm[ss * 32 + y]; btag[ss - 1] = y; }
    }
    __syncthreads();
    int q = tid;
    int y = btag[sseg];
    for (int p = 32 * sseg + 31; p >= q + 1; p--) y = bp[p * Ln + y];
    out[1 + (size_t)b * Tn + q] = (float)y;

    int lbl = label[(size_t)b * Tn + q];
    float tpf = (lbl > 0 && y == lbl) ? 1.f : 0.f;
    float tnf = (lbl > 0 && y != lbl) ? 1.f : 0.f;
    float fpf = (q < slen && lbl == 0 && y > 0) ? 1.f : 0.f;
    #pragma unroll
    for (int off = 32; off >= 1; off >>= 1) {
        tpf += __shfl_xor(tpf, off);
        tnf += __shfl_xor(tnf, off);
        fpf += __shfl_xor(fpf, off);
    }
    if (lane == 0) { credA[wv] = tpf; credB[wv] = tnf; credC[wv] = fpf; }
    __syncthreads();
    if (tid == 0) {
        float aa = 0.f, bb2 = 0.f, cc2 = 0.f;
        #pragma unroll
        for (int w = 0; w < 8; w++) { aa += credA[w]; bb2 += credB[w]; cc2 += credC[w]; }
        wsf[CNT_OFF + b] = aa;
        wsf[CNT_OFF + Bn + b] = bb2;
        wsf[CNT_OFF + 2 * Bn + b] = cc2;
    }
}

// ---------------------------------------------------------------------------
// Kernel 3: final scalar reductions
// ---------------------------------------------------------------------------
__global__ __launch_bounds__(64) void crf_final(const float* __restrict__ wsf,
                                                float* __restrict__ out)
{
    int lane = threadIdx.x;
    float nll = wsf[LOGNORM_OFF + lane] - wsf[SCORE_OFF + lane];
    float tp = wsf[CNT_OFF + lane];
    float tn = wsf[CNT_OFF + Bn + lane];
    float fp = wsf[CNT_OFF + 2 * Bn + lane];
    #pragma unroll
    for (int off = 32; off >= 1; off >>= 1) {
        nll += __shfl_xor(nll, off);
        tp  += __shfl_xor(tp, off);
        tn  += __shfl_xor(tn, off);
        fp  += __shfl_xor(fp, off);
    }
    if (lane == 0) {
        out[0] = nll * (1.f / 64.f);
        out[1 + Bn * Tn + 0] = tp;
        out[1 + Bn * Tn + 1] = tn;
        out[1 + Bn * Tn + 2] = fp;
    }
}

extern "C" void kernel_launch(void* const* d_in, const int* in_sizes, int n_in,
                              void* d_out, int out_size, void* d_ws, size_t ws_size,
                              hipStream_t stream) {
    const float* x     = (const float*)d_in[0];
    const float* W     = (const float*)d_in[1];
    const float* bias  = (const float*)d_in[2];
    const float* trans = (const float*)d_in[3];
    const int* label   = (const int*)d_in[4];
    const int* seqlen  = (const int*)d_in[5];
    float* out = (float*)d_out;
    float* wsf = (float*)d_ws;

    gemm_emis<<<dim3(Bn * (Tn / BM)), dim3(256), 0, stream>>>(x, W, bias, seqlen, wsf + EMIS_OFF);
    crf_forward<<<dim3(Bn), dim3(512), 0, stream>>>(wsf + EMIS_OFF, trans, label, seqlen, out, wsf);
    crf_final<<<dim3(1), dim3(64), 0, stream>>>(wsf, out);
}

// Round 4
// 286.348 us; speedup vs baseline: 1.3774x; 1.0302x over previous
//
#include <hip/hip_runtime.h>
#include <stdint.h>
#include <math.h>

#define Bn 64
#define Tn 512
#define Dn 1024
#define Ln 32
#define LOG2E 1.4426950408889634f
#define LN2f  0.6931471805599453f

// workspace float offsets
#define EMIS_OFF 0
#define LOGNORM_OFF (Bn * Tn * Ln)
#define SCORE_OFF (LOGNORM_OFF + Bn)
#define CNT_OFF (SCORE_OFF + Bn)

// max3 helper: compiler fuses fmaxf(fmaxf(a,b),c) -> v_max3_f32
#define MAX3(a,b,c) fmaxf(fmaxf((a),(b)),(c))

// DPP row rotate (16-lane row), K = compile-time rotate amount.
template<int K>
__device__ __forceinline__ float rorf(float v) {
    return __int_as_float(__builtin_amdgcn_update_dpp(
        0, __float_as_int(v), 0x120 | K, 0xF, 0xF, true));
}

// Opaque register copy: compiler cannot prove r == v, so r gets a distinct
// physical register from any other live copy of v. This is the R3 bugfix:
// without it, the two swap operands (same value) could be coalesced into ONE
// register, turning the permlane swap into an in-place rotation (combine then
// loses the lane's own partial; probe polarity diverges from loop sites).
__device__ __forceinline__ float opaque_copy(float v) {
    float r;
    asm volatile("v_mov_b32 %0, %1" : "=v"(r) : "v"(v));
    return r;
}

// cross-lane half swap (lanes 0-31 <-> 32-63): after the op, {x,y} hold
// {own, other} in some order on every lane.
__device__ __forceinline__ void swap32p(float p, float& x, float& y) {
    x = p;
    y = opaque_copy(p);
    asm volatile("v_permlane32_swap_b32 %0, %1" : "+v"(x), "+v"(y));
}
// 16-lane-row pair swap primitive; exact routing probed at runtime.
__device__ __forceinline__ void swap16p(float p, float& x, float& y) {
    x = p;
    y = opaque_copy(p);
    asm volatile("v_permlane16_swap_b32 %0, %1" : "+v"(x), "+v"(y));
}

// ---------------------------------------------------------------------------
// Kernel 1: emissions = x @ W + bias. 256 blocks x 256 threads. (unchanged)
// ---------------------------------------------------------------------------
#define BM 128
#define KB 32
#define XSS 132

__global__ __launch_bounds__(256) void gemm_emis(
    const float* __restrict__ x, const float* __restrict__ Wm,
    const float* __restrict__ bias, const int* __restrict__ seqlen,
    float* __restrict__ emis)
{
    int b  = blockIdx.x >> 2;
    int t0 = (blockIdx.x & 3) * BM;
    if (t0 >= seqlen[b]) return;

    __shared__ __align__(16) float xs[KB * XSS];   // transposed: xs[k][row]
    __shared__ __align__(16) float wsh[KB * Ln];   // wsh[k][col]

    int tid = threadIdx.x;
    int cg = tid & 7;       // cols 4cg..4cg+3
    int rg = tid >> 3;      // rows 4rg..4rg+3 (0..31)

    const float* xrow = x + (size_t)(b * Tn + t0) * Dn;

    float acc[4][4];
    #pragma unroll
    for (int z = 0; z < 4; z++)
        #pragma unroll
        for (int c = 0; c < 4; c++) acc[z][c] = 0.f;

    // prologue: prefetch chunk 0 into registers
    float4 xr[4]; float4 wr;
    #pragma unroll
    for (int u = 0; u < 4; u++) {
        int f = tid + 256 * u;
        xr[u] = *(const float4*)(xrow + (size_t)(f >> 3) * Dn + (f & 7) * 4);
    }
    wr = *(const float4*)(Wm + tid * 4);

    for (int k0 = 0; k0 < Dn; k0 += KB) {
        __syncthreads();
        #pragma unroll
        for (int u = 0; u < 4; u++) {
            int f = tid + 256 * u;
            int lrow = f >> 3, kk = f & 7;
            xs[(4 * kk + 0) * XSS + lrow] = xr[u].x;
            xs[(4 * kk + 1) * XSS + lrow] = xr[u].y;
            xs[(4 * kk + 2) * XSS + lrow] = xr[u].z;
            xs[(4 * kk + 3) * XSS + lrow] = xr[u].w;
        }
        *(float4*)(wsh + tid * 4) = wr;
        __syncthreads();

        int kn = k0 + KB;
        if (kn < Dn) {
            #pragma unroll
            for (int u = 0; u < 4; u++) {
                int f = tid + 256 * u;
                xr[u] = *(const float4*)(xrow + (size_t)(f >> 3) * Dn + kn + (f & 7) * 4);
            }
            wr = *(const float4*)(Wm + (size_t)kn * Ln + tid * 4);
        }

        #pragma unroll 8
        for (int k = 0; k < KB; k++) {
            float4 a = *(const float4*)(xs + k * XSS + 4 * rg);
            float4 w = *(const float4*)(wsh + k * Ln + 4 * cg);
            float av[4] = {a.x, a.y, a.z, a.w};
            float wv[4] = {w.x, w.y, w.z, w.w};
            #pragma unroll
            for (int z = 0; z < 4; z++)
                #pragma unroll
                for (int c = 0; c < 4; c++)
                    acc[z][c] = fmaf(av[z], wv[c], acc[z][c]);
        }
    }

    float4 bv = *(const float4*)(bias + 4 * cg);
    float bb[4] = {bv.x, bv.y, bv.z, bv.w};
    #pragma unroll
    for (int z = 0; z < 4; z++) {
        float4 o;
        o.x = acc[z][0] + bb[0];
        o.y = acc[z][1] + bb[1];
        o.z = acc[z][2] + bb[2];
        o.w = acc[z][3] + bb[3];
        *(float4*)(emis + (size_t)(b * Tn + t0 + 4 * rg + z) * Ln + 4 * cg) = o;
    }
}

// ---------------------------------------------------------------------------
// Kernel 2: per-batch CRF. grid 64 x 512. Chunked pipeline (CH=64):
//   wave0 = Viterbi, wave1 = log-norm, waves2-7 = seq-score then bp recompute.
// Scan recurrences fully in-register. 16-lane row r holds alphas
// [lo,lo,hi,hi] (r0,r1: a_0..15; r2,r3: a_16..31). Per step:
//   - gather within row via DPP row_ror fused adds (VALU, no LDS),
//   - combine complementary rows (r0<->r2, r1<->r3) via v_permlane32_swap,
//   - add emit, store al (off-chain), restore layout via v_permlane16_swap
//     + probed cndmask.
// DPP rotation direction and permlane16 routing are runtime-probed; swap
// operands forced into distinct registers via opaque_copy (R3 bugfix).
// ---------------------------------------------------------------------------
#define CH 64

__global__ __launch_bounds__(512) void crf_forward(
    const float* __restrict__ emis, const float* __restrict__ trans,
    const int* __restrict__ label, const int* __restrict__ seqlen,
    float* __restrict__ out, float* __restrict__ wsf)
{
    __shared__ __align__(16) float es[Tn * Ln];   // 64 KB emissions
    __shared__ __align__(16) float al[Tn * Ln];   // 64 KB alphas
    __shared__ __align__(16) float trs[Ln * Ln];  // 4 KB transitions
    __shared__ uint8_t bp[Tn * Ln];               // 16 KB backpointers
    __shared__ uint8_t Fm[16 * 32];
    __shared__ int btag[16];
    __shared__ int s_last;
    __shared__ float credA[8], credB[8], credC[8];

    int tid = threadIdx.x;
    int b = blockIdx.x;
    int slen = seqlen[b];
    int wv = tid >> 6;
    int lane = tid & 63;
    int j = lane & 31;

    const float* eb = emis + (size_t)b * Tn * Ln;

    {
        int n4 = slen * (Ln / 4);
        for (int i4 = tid; i4 < n4; i4 += 512)
            ((float4*)es)[i4] = ((const float4*)eb)[i4];
    }
    if (tid < 256) ((float4*)trs)[tid] = ((const float4*)trans)[tid];
    {
        uint32_t* bp32 = (uint32_t*)bp;
        for (int w = tid; w < Tn * Ln / 4; w += 512)
            bp32[w] = 0x03020100u + 0x04040404u * (uint32_t)(w & 7);
    }

    // ---- runtime probes (cheap, once) ----
    int rq[16];
    {
        float qf = (float)(lane & 15);
        rq[0]  = lane & 15;
        rq[1]  = (int)rorf<1>(qf);   rq[2]  = (int)rorf<2>(qf);
        rq[3]  = (int)rorf<3>(qf);   rq[4]  = (int)rorf<4>(qf);
        rq[5]  = (int)rorf<5>(qf);   rq[6]  = (int)rorf<6>(qf);
        rq[7]  = (int)rorf<7>(qf);   rq[8]  = (int)rorf<8>(qf);
        rq[9]  = (int)rorf<9>(qf);   rq[10] = (int)rorf<10>(qf);
        rq[11] = (int)rorf<11>(qf);  rq[12] = (int)rorf<12>(qf);
        rq[13] = (int)rorf<13>(qf);  rq[14] = (int)rorf<14>(qf);
        rq[15] = (int)rorf<15>(qf);
    }
    bool useX;
    {
        float px, py; swap16p((float)lane, px, py);
        useX = (px == (float)(lane ^ 16));
    }
    int hoff = (lane & 32) ? 16 : 0;             // held-set row offset
    int hidx = (lane & 15) + hoff;               // held state index h(l)
    int row2 = (lane >> 4) & 3;
    bool keepC = (row2 == 0) || (row2 == 3);     // rows 0,3 keep combined c

    __syncthreads();

    float av = 0.f, emit = 0.f;            // viterbi
    float a = 0.f, eemit = 0.f;            // LSE
    int   Eacc = 0;
    float tr[32];
    float e2[16];

    if (wv == 0) {
        #pragma unroll
        for (int k = 0; k < 16; k++) tr[k] = trs[(rq[k] + hoff) * Ln + j];
        av = es[hidx];
        al[hidx] = av;                     // dup-identical writes
        emit = es[Ln + j];
    } else if (wv == 1) {
        #pragma unroll
        for (int k = 0; k < 16; k++) e2[k] = exp2f(trs[(rq[k] + hoff) * Ln + j] * LOG2E);
        a = exp2f(es[hidx] * LOG2E);
        eemit = exp2f(es[Ln + j] * LOG2E);
    } else {
        #pragma unroll
        for (int i = 0; i < 32; i++) tr[i] = trs[i * Ln + j];
    }

    for (int c = 0; c < Tn / CH; c++) {
        int tb = (c == 0) ? 1 : c * CH;
        int te = (c + 1) * CH; if (te > slen) te = slen;

        if (wv == 0) {
            // ---------- Viterbi: DPP gather + max3 tree, no LDS on chain ----
            #pragma unroll 2
            for (int t = tb; t < te; t++) {
                int tnx = (t + 1 < slen) ? (t + 1) : (slen - 1);
                float emitn = es[tnx * Ln + j];        // off-chain prefetch
                float vv0  = av           + tr[0];
                float vv1  = rorf<1>(av)  + tr[1];
                float vv2  = rorf<2>(av)  + tr[2];
                float vv3  = rorf<3>(av)  + tr[3];
                float vv4  = rorf<4>(av)  + tr[4];
                float vv5  = rorf<5>(av)  + tr[5];
                float vv6  = rorf<6>(av)  + tr[6];
                float vv7  = rorf<7>(av)  + tr[7];
                float vv8  = rorf<8>(av)  + tr[8];
                float vv9  = rorf<9>(av)  + tr[9];
                float vv10 = rorf<10>(av) + tr[10];
                float vv11 = rorf<11>(av) + tr[11];
                float vv12 = rorf<12>(av) + tr[12];
                float vv13 = rorf<13>(av) + tr[13];
                float vv14 = rorf<14>(av) + tr[14];
                float vv15 = rorf<15>(av) + tr[15];
                float g0 = MAX3(vv0,  vv1,  vv2);
                float g1 = MAX3(vv3,  vv4,  vv5);
                float g2 = MAX3(vv6,  vv7,  vv8);
                float g3 = MAX3(vv9,  vv10, vv11);
                float g4 = MAX3(vv12, vv13, vv14);
                float h0 = MAX3(g0, g1, g2);
                float h1 = MAX3(g3, g4, vv15);
                float p = fmaxf(h0, h1);
                float x, y; swap32p(p, x, y);          // combine r0<->r2, r1<->r3
                float cmb = fmaxf(x, y) + emit;        // a'_{j(l)}, layout [lo,hi,lo,hi]
                al[t * Ln + j] = cmb;                  // off-chain, dup-identical
                float x2, y2; swap16p(cmb, x2, y2);    // row-pair swap
                float z = useX ? x2 : y2;              // value from lane^16
                av = keepC ? cmb : z;                  // restore [lo,lo,hi,hi]
                emit = emitn;
            }
        } else if (wv == 1) {
            // ---------- LSE: DPP gather, shifted-linear ----------
            #pragma unroll 2
            for (int t = tb; t < te; t++) {
                int tnx = (t + 1 < slen) ? (t + 1) : (slen - 1);
                float emitn = es[tnx * Ln + j];
                float eemitn = exp2f(emitn * LOG2E);   // off-chain
                float s0 = a           * e2[0];
                float s1 = rorf<1>(a)  * e2[1];
                float s2 = rorf<2>(a)  * e2[2];
                float s3 = rorf<3>(a)  * e2[3];
                s0 = fmaf(rorf<4>(a),  e2[4],  s0);
                s1 = fmaf(rorf<5>(a),  e2[5],  s1);
                s2 = fmaf(rorf<6>(a),  e2[6],  s2);
                s3 = fmaf(rorf<7>(a),  e2[7],  s3);
                s0 = fmaf(rorf<8>(a),  e2[8],  s0);
                s1 = fmaf(rorf<9>(a),  e2[9],  s1);
                s2 = fmaf(rorf<10>(a), e2[10], s2);
                s3 = fmaf(rorf<11>(a), e2[11], s3);
                s0 = fmaf(rorf<12>(a), e2[12], s0);
                s1 = fmaf(rorf<13>(a), e2[13], s1);
                s2 = fmaf(rorf<14>(a), e2[14], s2);
                s3 = fmaf(rorf<15>(a), e2[15], s3);
                float pp = (s0 + s1) + (s2 + s3);
                float x, y; swap32p(pp, x, y);
                float s = (x + y) * eemit;
                float an;
                if ((t & 3) == 0) {   // pow2 renorm every 4 steps (range-safe)
                    unsigned sb = (unsigned)__builtin_amdgcn_readfirstlane(__float_as_int(s));
                    int e = (int)((sb >> 23) & 0xFFu) - 127;
                    Eacc += e;
                    an = ldexpf(s, -e);
                } else {
                    an = s;
                }
                float x2, y2; swap16p(an, x2, y2);
                float z = useX ? x2 : y2;
                a = keepC ? an : z;
                eemit = eemitn;
            }
        } else if (c == 0) {
            if (wv == 2) {
                const int* lb = label + (size_t)b * Tn;
                float acc = 0.f;
                for (int t = lane; t < Tn; t += 64) {
                    if (t < slen) {
                        int lc = lb[t];
                        acc += es[t * Ln + lc];
                        if (t >= 1) acc += trs[lb[t - 1] * Ln + lc];
                    }
                }
                #pragma unroll
                for (int off = 32; off >= 1; off >>= 1) acc += __shfl_xor(acc, off);
                if (lane == 0) wsf[SCORE_OFF + b] = acc;
            }
        } else {
            // ---------- bp recompute for chunk c-1 (12 stripes) ----------
            int stripe = (wv - 2) * 2 + (lane >> 5);
            int pb = ((c - 1) == 0) ? 1 : (c - 1) * CH;
            int pe = c * CH; if (pe > slen) pe = slen;
            for (int t = pb + stripe; t < pe; t += 12) {
                const float* ar = al + (t - 1) * Ln;
                float vv[32];
                #pragma unroll
                for (int i = 0; i < 32; i += 4) {
                    float4 a4 = *(const float4*)(ar + i);
                    vv[i]     = a4.x + tr[i];
                    vv[i + 1] = a4.y + tr[i + 1];
                    vv[i + 2] = a4.z + tr[i + 2];
                    vv[i + 3] = a4.w + tr[i + 3];
                }
                float mv[16]; int mi[16];
                #pragma unroll
                for (int i = 0; i < 16; i++) {
                    bool g = vv[2*i+1] > vv[2*i];
                    mv[i] = g ? vv[2*i+1] : vv[2*i];
                    mi[i] = g ? (2*i+1) : (2*i);
                }
                #pragma unroll
                for (int i = 0; i < 8; i++) {
                    bool g = mv[2*i+1] > mv[2*i];
                    mv[i] = g ? mv[2*i+1] : mv[2*i];
                    mi[i] = g ? mi[2*i+1] : mi[2*i];
                }
                #pragma unroll
                for (int i = 0; i < 4; i++) {
                    bool g = mv[2*i+1] > mv[2*i];
                    mv[i] = g ? mv[2*i+1] : mv[2*i];
                    mi[i] = g ? mi[2*i+1] : mi[2*i];
                }
                #pragma unroll
                for (int i = 0; i < 2; i++) {
                    bool g = mv[2*i+1] > mv[2*i];
                    mv[i] = g ? mv[2*i+1] : mv[2*i];
                    mi[i] = g ? mi[2*i+1] : mi[2*i];
                }
                bp[t * Ln + j] = (uint8_t)mi[0];
            }
        }
        __syncthreads();
    }

    // tail
    if (wv == 0) {
        // av holds a'_{hidx}, each state twice; tie-break lowest state index
        float mm = av; int ai = hidx;
        #pragma unroll
        for (int off = 32; off >= 1; off >>= 1) {
            float om = __shfl_xor(mm, off);
            int   oi = __shfl_xor(ai, off);
            if (om > mm || (om == mm && oi < ai)) { mm = om; ai = oi; }
        }
        if (lane == 0) s_last = ai;
    } else if (wv == 1) {
        // 64-lane sum counts each state twice -> subtract 1 from log2
        float ss = a;
        #pragma unroll
        for (int off = 32; off >= 1; off >>= 1) ss += __shfl_xor(ss, off);
        if (lane == 0)
            wsf[LOGNORM_OFF + b] = (log2f(ss) - 1.0f + (float)Eacc) * LN2f;
    } else {
        int stripe = (wv - 2) * 2 + (lane >> 5);
        int cc = Tn / CH - 1;
        int pb = cc * CH;
        int pe = Tn; if (pe > slen) pe = slen;
        for (int t = pb + stripe; t < pe; t += 12) {
            const float* ar = al + (t - 1) * Ln;
            float vv[32];
            #pragma unroll
            for (int i = 0; i < 32; i += 4) {
                float4 a4 = *(const float4*)(ar + i);
                vv[i]     = a4.x + tr[i];
                vv[i + 1] = a4.y + tr[i + 1];
                vv[i + 2] = a4.z + tr[i + 2];
                vv[i + 3] = a4.w + tr[i + 3];
            }
            float mv[16]; int mi[16];
            #pragma unroll
            for (int i = 0; i < 16; i++) {
                bool g = vv[2*i+1] > vv[2*i];
                mv[i] = g ? vv[2*i+1] : vv[2*i];
                mi[i] = g ? (2*i+1) : (2*i);
            }
            #pragma unroll
            for (int i = 0; i < 8; i++) {
                bool g = mv[2*i+1] > mv[2*i];
                mv[i] = g ? mv[2*i+1] : mv[2*i];
                mi[i] = g ? mi[2*i+1] : mi[2*i];
            }
            #pragma unroll
            for (int i = 0; i < 4; i++) {
                bool g = mv[2*i+1] > mv[2*i];
                mv[i] = g ? mv[2*i+1] : mv[2*i];
                mi[i] = g ? mi[2*i+1] : mi[2*i];
            }
            #pragma unroll
            for (int i = 0; i < 2; i++) {
                bool g = mv[2*i+1] > mv[2*i];
                mv[i] = g ? mv[2*i+1] : mv[2*i];
                mi[i] = g ? mi[2*i+1] : mi[2*i];
            }
            bp[t * Ln + j] = (uint8_t)mi[0];
        }
    }
    __syncthreads();

    // ---------------- segmented parallel backtrace ----------------
    int sseg = tid >> 5, ent = tid & 31;
    {
        int y = ent;
        for (int p = 32 * sseg + 31; p >= 32 * sseg; p--) y = bp[p * Ln + y];
        Fm[sseg * 32 + ent] = (uint8_t)y;
    }
    __syncthreads();
    if (tid == 0) {
        int y = s_last;
        btag[15] = y;
        for (int ss = 15; ss >= 1; ss--) { y = Fm[ss * 32 + y]; btag[ss - 1] = y; }
    }
    __syncthreads();
    int q = tid;
    int y = btag[sseg];
    for (int p = 32 * sseg + 31; p >= q + 1; p--) y = bp[p * Ln + y];
    out[1 + (size_t)b * Tn + q] = (float)y;

    int lbl = label[(size_t)b * Tn + q];
    float tpf = (lbl > 0 && y == lbl) ? 1.f : 0.f;
    float tnf = (lbl > 0 && y != lbl) ? 1.f : 0.f;
    float fpf = (q < slen && lbl == 0 && y > 0) ? 1.f : 0.f;
    #pragma unroll
    for (int off = 32; off >= 1; off >>= 1) {
        tpf += __shfl_xor(tpf, off);
        tnf += __shfl_xor(tnf, off);
        fpf += __shfl_xor(fpf, off);
    }
    if (lane == 0) { credA[wv] = tpf; credB[wv] = tnf; credC[wv] = fpf; }
    __syncthreads();
    if (tid == 0) {
        float aa = 0.f, bb2 = 0.f, cc2 = 0.f;
        #pragma unroll
        for (int w = 0; w < 8; w++) { aa += credA[w]; bb2 += credB[w]; cc2 += credC[w]; }
        wsf[CNT_OFF + b] = aa;
        wsf[CNT_OFF + Bn + b] = bb2;
        wsf[CNT_OFF + 2 * Bn + b] = cc2;
    }
}

// ---------------------------------------------------------------------------
// Kernel 3: final scalar reductions
// ---------------------------------------------------------------------------
__global__ __launch_bounds__(64) void crf_final(const float* __restrict__ wsf,
                                                float* __restrict__ out)
{
    int lane = threadIdx.x;
    float nll = wsf[LOGNORM_OFF + lane] - wsf[SCORE_OFF + lane];
    float tp = wsf[CNT_OFF + lane];
    float tn = wsf[CNT_OFF + Bn + lane];
    float fp = wsf[CNT_OFF + 2 * Bn + lane];
    #pragma unroll
    for (int off = 32; off >= 1; off >>= 1) {
        nll += __shfl_xor(nll, off);
        tp  += __shfl_xor(tp, off);
        tn  += __shfl_xor(tn, off);
        fp  += __shfl_xor(fp, off);
    }
    if (lane == 0) {
        out[0] = nll * (1.f / 64.f);
        out[1 + Bn * Tn + 0] = tp;
        out[1 + Bn * Tn + 1] = tn;
        out[1 + Bn * Tn + 2] = fp;
    }
}

extern "C" void kernel_launch(void* const* d_in, const int* in_sizes, int n_in,
                              void* d_out, int out_size, void* d_ws, size_t ws_size,
                              hipStream_t stream) {
    const float* x     = (const float*)d_in[0];
    const float* W     = (const float*)d_in[1];
    const float* bias  = (const float*)d_in[2];
    const float* trans = (const float*)d_in[3];
    const int* label   = (const int*)d_in[4];
    const int* seqlen  = (const int*)d_in[5];
    float* out = (float*)d_out;
    float* wsf = (float*)d_ws;

    gemm_emis<<<dim3(Bn * (Tn / BM)), dim3(256), 0, stream>>>(x, W, bias, seqlen, wsf + EMIS_OFF);
    crf_forward<<<dim3(Bn), dim3(512), 0, stream>>>(wsf + EMIS_OFF, trans, label, seqlen, out, wsf);
    crf_final<<<dim3(1), dim3(64), 0, stream>>>(wsf, out);
}

// Round 6
// 271.653 us; speedup vs baseline: 1.4519x; 1.0541x over previous
//
#include <hip/hip_runtime.h>
#include <stdint.h>
#include <math.h>

#define Bn 64
#define Tn 512
#define Dn 1024
#define Ln 32
#define LOG2E 1.4426950408889634f
#define LN2f  0.6931471805599453f

// workspace float offsets
#define EMIS_OFF 0
#define LOGNORM_OFF (Bn * Tn * Ln)
#define SCORE_OFF (LOGNORM_OFF + Bn)
#define CNT_OFF (SCORE_OFF + Bn)

// max3 helper: compiler fuses fmaxf(fmaxf(a,b),c) -> v_max3_f32
#define MAX3(a,b,c) fmaxf(fmaxf((a),(b)),(c))

// DPP row rotate (16-lane row), K = compile-time rotate amount.
template<int K>
__device__ __forceinline__ float rorf(float v) {
    return __int_as_float(__builtin_amdgcn_update_dpp(
        0, __float_as_int(v), 0x120 | K, 0xF, 0xF, true));
}

// Opaque register copy: compiler cannot prove r == v, so the two swap
// operands land in distinct physical registers (R3 bugfix, R4-verified).
// Non-volatile: pure value function, scheduler may move it freely.
__device__ __forceinline__ float opaque_copy(float v) {
    float r;
    asm("v_mov_b32 %0, %1" : "=v"(r) : "v"(v));
    return r;
}

// cross-lane swaps; after the op {x,y} hold {own, other} in some order on
// every lane, so a commutative combine needs no polarity select.
// Non-volatile: value-pure, lets the scheduler overlap across iterations.
__device__ __forceinline__ void swap32p(float p, float& x, float& y) {
    x = p;
    y = opaque_copy(p);
    asm("v_permlane32_swap_b32 %0, %1" : "+v"(x), "+v"(y));
}
__device__ __forceinline__ void swap16p(float p, float& x, float& y) {
    x = p;
    y = opaque_copy(p);
    asm("v_permlane16_swap_b32 %0, %1" : "+v"(x), "+v"(y));
}

// ---------------------------------------------------------------------------
// Kernel 1: emissions = x @ W + bias. 256 blocks x 256 threads. (unchanged)
// ---------------------------------------------------------------------------
#define BM 128
#define KB 32
#define XSS 132

__global__ __launch_bounds__(256) void gemm_emis(
    const float* __restrict__ x, const float* __restrict__ Wm,
    const float* __restrict__ bias, const int* __restrict__ seqlen,
    float* __restrict__ emis)
{
    int b  = blockIdx.x >> 2;
    int t0 = (blockIdx.x & 3) * BM;
    if (t0 >= seqlen[b]) return;

    __shared__ __align__(16) float xs[KB * XSS];   // transposed: xs[k][row]
    __shared__ __align__(16) float wsh[KB * Ln];   // wsh[k][col]

    int tid = threadIdx.x;
    int cg = tid & 7;       // cols 4cg..4cg+3
    int rg = tid >> 3;      // rows 4rg..4rg+3 (0..31)

    const float* xrow = x + (size_t)(b * Tn + t0) * Dn;

    float acc[4][4];
    #pragma unroll
    for (int z = 0; z < 4; z++)
        #pragma unroll
        for (int c = 0; c < 4; c++) acc[z][c] = 0.f;

    // prologue: prefetch chunk 0 into registers
    float4 xr[4]; float4 wr;
    #pragma unroll
    for (int u = 0; u < 4; u++) {
        int f = tid + 256 * u;
        xr[u] = *(const float4*)(xrow + (size_t)(f >> 3) * Dn + (f & 7) * 4);
    }
    wr = *(const float4*)(Wm + tid * 4);

    for (int k0 = 0; k0 < Dn; k0 += KB) {
        __syncthreads();
        #pragma unroll
        for (int u = 0; u < 4; u++) {
            int f = tid + 256 * u;
            int lrow = f >> 3, kk = f & 7;
            xs[(4 * kk + 0) * XSS + lrow] = xr[u].x;
            xs[(4 * kk + 1) * XSS + lrow] = xr[u].y;
            xs[(4 * kk + 2) * XSS + lrow] = xr[u].z;
            xs[(4 * kk + 3) * XSS + lrow] = xr[u].w;
        }
        *(float4*)(wsh + tid * 4) = wr;
        __syncthreads();

        int kn = k0 + KB;
        if (kn < Dn) {
            #pragma unroll
            for (int u = 0; u < 4; u++) {
                int f = tid + 256 * u;
                xr[u] = *(const float4*)(xrow + (size_t)(f >> 3) * Dn + kn + (f & 7) * 4);
            }
            wr = *(const float4*)(Wm + (size_t)kn * Ln + tid * 4);
        }

        #pragma unroll 8
        for (int k = 0; k < KB; k++) {
            float4 a = *(const float4*)(xs + k * XSS + 4 * rg);
            float4 w = *(const float4*)(wsh + k * Ln + 4 * cg);
            float av[4] = {a.x, a.y, a.z, a.w};
            float wv[4] = {w.x, w.y, w.z, w.w};
            #pragma unroll
            for (int z = 0; z < 4; z++)
                #pragma unroll
                for (int c = 0; c < 4; c++)
                    acc[z][c] = fmaf(av[z], wv[c], acc[z][c]);
        }
    }

    float4 bv = *(const float4*)(bias + 4 * cg);
    float bb[4] = {bv.x, bv.y, bv.z, bv.w};
    #pragma unroll
    for (int z = 0; z < 4; z++) {
        float4 o;
        o.x = acc[z][0] + bb[0];
        o.y = acc[z][1] + bb[1];
        o.z = acc[z][2] + bb[2];
        o.w = acc[z][3] + bb[3];
        *(float4*)(emis + (size_t)(b * Tn + t0 + 4 * rg + z) * Ln + 4 * cg) = o;
    }
}

// ---------------------------------------------------------------------------
// Kernel 2: per-batch CRF. grid 64 x 512. Chunked pipeline (CH=64):
//   wave0 = Viterbi, wave1 = log-norm, waves2-7 = seq-score then bp recompute.
// R5: alternating-butterfly in-register scan. Odd steps (A): sources split by
// lane-bit5, outputs indexed o4=(q|bit4<<4), combine via v_permlane32_swap ->
// result lands in bit4 layout. Even steps (B): sources split by bit4, outputs
// o5, combine via v_permlane16_swap -> bit5 layout (= A's input). No restore
// step ever. Two preloaded tr variants (trA/trB). Emit prefetch distance 2
// (same parity => same column index). Swap asms non-volatile (scheduler free).
// ---------------------------------------------------------------------------
#define CH 64

// Viterbi step. TRARR matches layout; SWAPFN combines across the source bit;
// OE = output/emit/al column index for this parity.
#define VIT_BODY(T, TRARR, SWAPFN, OE)                                       \
  {                                                                          \
    int tnx2 = ((T) + 2 < slen) ? ((T) + 2) : (slen - 1);                    \
    float e2n = es[tnx2 * Ln + (OE)];                                        \
    float vv0  = av            + TRARR[0];                                   \
    float vv1  = rorf<1>(av)   + TRARR[1];                                   \
    float vv2  = rorf<2>(av)   + TRARR[2];                                   \
    float vv3  = rorf<3>(av)   + TRARR[3];                                   \
    float vv4  = rorf<4>(av)   + TRARR[4];                                   \
    float vv5  = rorf<5>(av)   + TRARR[5];                                   \
    float vv6  = rorf<6>(av)   + TRARR[6];                                   \
    float vv7  = rorf<7>(av)   + TRARR[7];                                   \
    float vv8  = rorf<8>(av)   + TRARR[8];                                   \
    float vv9  = rorf<9>(av)   + TRARR[9];                                   \
    float vv10 = rorf<10>(av)  + TRARR[10];                                  \
    float vv11 = rorf<11>(av)  + TRARR[11];                                  \
    float vv12 = rorf<12>(av)  + TRARR[12];                                  \
    float vv13 = rorf<13>(av)  + TRARR[13];                                  \
    float vv14 = rorf<14>(av)  + TRARR[14];                                  \
    float vv15 = rorf<15>(av)  + TRARR[15];                                  \
    float g0 = MAX3(vv0,  vv1,  vv2);                                        \
    float g1 = MAX3(vv3,  vv4,  vv5);                                        \
    float g2 = MAX3(vv6,  vv7,  vv8);                                        \
    float g3 = MAX3(vv9,  vv10, vv11);                                       \
    float g4 = MAX3(vv12, vv13, vv14);                                       \
    float h0 = MAX3(g0, g1, g2);                                             \
    float h1 = MAX3(g3, g4, vv15);                                           \
    float p = fmaxf(h0, h1);                                                 \
    float xx, yy; SWAPFN(p, xx, yy);                                         \
    float cmb = fmaxf(xx, yy) + emit;                                        \
    al[(T) * Ln + (OE)] = cmb;                                               \
    av = cmb;                                                                \
    emit = emitn; emitn = e2n;                                               \
  }

// LSE step (shifted-linear). DORENORM compile-time gates the mod-4 renorm
// (only even steps can hit t%4==0).
#define LSE_BODY(T, EARR, SWAPFN, OE, DORENORM)                              \
  {                                                                          \
    int tnx2 = ((T) + 2 < slen) ? ((T) + 2) : (slen - 1);                    \
    float rawn = es[tnx2 * Ln + (OE)];                                       \
    float een = exp2f(rawnext * LOG2E);                                      \
    float s0 = a           * EARR[0];                                        \
    float s1 = rorf<1>(a)  * EARR[1];                                        \
    float s2 = rorf<2>(a)  * EARR[2];                                        \
    float s3 = rorf<3>(a)  * EARR[3];                                        \
    s0 = fmaf(rorf<4>(a),  EARR[4],  s0);                                    \
    s1 = fmaf(rorf<5>(a),  EARR[5],  s1);                                    \
    s2 = fmaf(rorf<6>(a),  EARR[6],  s2);                                    \
    s3 = fmaf(rorf<7>(a),  EARR[7],  s3);                                    \
    s0 = fmaf(rorf<8>(a),  EARR[8],  s0);                                    \
    s1 = fmaf(rorf<9>(a),  EARR[9],  s1);                                    \
    s2 = fmaf(rorf<10>(a), EARR[10], s2);                                    \
    s3 = fmaf(rorf<11>(a), EARR[11], s3);                                    \
    s0 = fmaf(rorf<12>(a), EARR[12], s0);                                    \
    s1 = fmaf(rorf<13>(a), EARR[13], s1);                                    \
    s2 = fmaf(rorf<14>(a), EARR[14], s2);                                    \
    s3 = fmaf(rorf<15>(a), EARR[15], s3);                                    \
    float pp = (s0 + s1) + (s2 + s3);                                        \
    float xx, yy; SWAPFN(pp, xx, yy);                                        \
    float s = (xx + yy) * eemit;                                             \
    if ((DORENORM) && (((T) & 3) == 0)) {                                    \
        unsigned sb = (unsigned)__builtin_amdgcn_readfirstlane(__float_as_int(s)); \
        int e = (int)((sb >> 23) & 0xFFu) - 127;                             \
        Eacc += e;                                                           \
        a = ldexpf(s, -e);                                                   \
    } else {                                                                 \
        a = s;                                                               \
    }                                                                        \
    eemit = een; rawnext = rawn;                                             \
  }

__global__ __launch_bounds__(512) void crf_forward(
    const float* __restrict__ emis, const float* __restrict__ trans,
    const int* __restrict__ label, const int* __restrict__ seqlen,
    float* __restrict__ out, float* __restrict__ wsf)
{
    __shared__ __align__(16) float es[Tn * Ln];   // 64 KB emissions
    __shared__ __align__(16) float al[Tn * Ln];   // 64 KB alphas
    __shared__ __align__(16) float trs[Ln * Ln];  // 4 KB transitions
    __shared__ uint8_t bp[Tn * Ln];               // 16 KB backpointers
    __shared__ uint8_t Fm[16 * 32];
    __shared__ int btag[16];
    __shared__ int s_last;
    __shared__ float credA[8], credB[8], credC[8];

    int tid = threadIdx.x;
    int b = blockIdx.x;
    int slen = seqlen[b];
    int wv = tid >> 6;
    int lane = tid & 63;
    int j = lane & 31;

    const float* eb = emis + (size_t)b * Tn * Ln;

    {
        int n4 = slen * (Ln / 4);
        for (int i4 = tid; i4 < n4; i4 += 512)
            ((float4*)es)[i4] = ((const float4*)eb)[i4];
    }
    if (tid < 256) ((float4*)trs)[tid] = ((const float4*)trans)[tid];
    {
        uint32_t* bp32 = (uint32_t*)bp;
        for (int w = tid; w < Tn * Ln / 4; w += 512)
            bp32[w] = 0x03020100u + 0x04040404u * (uint32_t)(w & 7);
    }

    // ---- runtime probe of DPP rotation direction (once; R4-verified) ----
    int rq[16];
    {
        float qf = (float)(lane & 15);
        rq[0]  = lane & 15;
        rq[1]  = (int)rorf<1>(qf);   rq[2]  = (int)rorf<2>(qf);
        rq[3]  = (int)rorf<3>(qf);   rq[4]  = (int)rorf<4>(qf);
        rq[5]  = (int)rorf<5>(qf);   rq[6]  = (int)rorf<6>(qf);
        rq[7]  = (int)rorf<7>(qf);   rq[8]  = (int)rorf<8>(qf);
        rq[9]  = (int)rorf<9>(qf);   rq[10] = (int)rorf<10>(qf);
        rq[11] = (int)rorf<11>(qf);  rq[12] = (int)rorf<12>(qf);
        rq[13] = (int)rorf<13>(qf);  rq[14] = (int)rorf<14>(qf);
        rq[15] = (int)rorf<15>(qf);
    }
    int q4  = lane & 15;
    int sb4 = (lane & 16) ? 16 : 0;   // bit4 source-block offset
    int sb5 = (lane & 32) ? 16 : 0;   // bit5 source-block offset
    int o4  = q4 + sb4;               // output col for A(odd) steps
    int o5  = q4 + sb5;               // output col for B(even) steps / init

    __syncthreads();

    float av = 0.f, emit = 0.f, emitn = 0.f;          // viterbi
    float a = 0.f, eemit = 0.f, rawnext = 0.f;        // LSE
    int   Eacc = 0;
    float trA[16], trB[16];
    float e2A[16], e2B[16];
    float trH[32];                                     // helpers

    int i1 = (1 < slen) ? 1 : (slen - 1);
    int i2 = (2 < slen) ? 2 : (slen - 1);

    if (wv == 0) {
        #pragma unroll
        for (int k = 0; k < 16; k++) {
            trA[k] = trs[(rq[k] + sb5) * Ln + o4];
            trB[k] = trs[(rq[k] + sb4) * Ln + o5];
        }
        av = es[o5];                  // alpha0, bit5 layout (step-1 input)
        al[o5] = av;                  // dup-identical writes
        emit  = es[i1 * Ln + o4];     // for t=1 (A)
        emitn = es[i2 * Ln + o5];     // for t=2 (B)
    } else if (wv == 1) {
        #pragma unroll
        for (int k = 0; k < 16; k++) {
            e2A[k] = exp2f(trs[(rq[k] + sb5) * Ln + o4] * LOG2E);
            e2B[k] = exp2f(trs[(rq[k] + sb4) * Ln + o5] * LOG2E);
        }
        a = exp2f(es[o5] * LOG2E);
        eemit   = exp2f(es[i1 * Ln + o4] * LOG2E);    // for t=1 (A)
        rawnext = es[i2 * Ln + o5];                   // for t=2 (B)
    } else {
        #pragma unroll
        for (int i = 0; i < 32; i++) trH[i] = trs[i * Ln + j];
    }

    for (int c = 0; c < Tn / CH; c++) {
        int tb = (c == 0) ? 1 : c * CH;
        int te = (c + 1) * CH; if (te > slen) te = slen;

        if (wv == 0) {
            int t = tb;
            if ((t & 1) && t < te) { VIT_BODY(t, trA, swap32p, o4); t++; }
            for (; t + 1 < te; t += 2) {
                VIT_BODY(t,     trB, swap16p, o5);
                VIT_BODY(t + 1, trA, swap32p, o4);
            }
            if (t < te) { VIT_BODY(t, trB, swap16p, o5); }
        } else if (wv == 1) {
            int t = tb;
            if ((t & 1) && t < te) { LSE_BODY(t, e2A, swap32p, o4, 0); t++; }
            for (; t + 1 < te; t += 2) {
                LSE_BODY(t,     e2B, swap16p, o5, 1);
                LSE_BODY(t + 1, e2A, swap32p, o4, 0);
            }
            if (t < te) { LSE_BODY(t, e2B, swap16p, o5, 1); }
        } else if (c == 0) {
            if (wv == 2) {
                const int* lb = label + (size_t)b * Tn;
                float acc = 0.f;
                for (int t = lane; t < Tn; t += 64) {
                    if (t < slen) {
                        int lc = lb[t];
                        acc += es[t * Ln + lc];
                        if (t >= 1) acc += trs[lb[t - 1] * Ln + lc];
                    }
                }
                #pragma unroll
                for (int off = 32; off >= 1; off >>= 1) acc += __shfl_xor(acc, off);
                if (lane == 0) wsf[SCORE_OFF + b] = acc;
            }
        } else {
            // ---------- bp recompute for chunk c-1 (12 stripes) ----------
            int stripe = (wv - 2) * 2 + (lane >> 5);
            int pb = ((c - 1) == 0) ? 1 : (c - 1) * CH;
            int pe = c * CH; if (pe > slen) pe = slen;
            for (int t = pb + stripe; t < pe; t += 12) {
                const float* ar = al + (t - 1) * Ln;
                float vv[32];
                #pragma unroll
                for (int i = 0; i < 32; i += 4) {
                    float4 a4 = *(const float4*)(ar + i);
                    vv[i]     = a4.x + trH[i];
                    vv[i + 1] = a4.y + trH[i + 1];
                    vv[i + 2] = a4.z + trH[i + 2];
                    vv[i + 3] = a4.w + trH[i + 3];
                }
                float mv[16]; int mi[16];
                #pragma unroll
                for (int i = 0; i < 16; i++) {
                    bool g = vv[2*i+1] > vv[2*i];
                    mv[i] = g ? vv[2*i+1] : vv[2*i];
                    mi[i] = g ? (2*i+1) : (2*i);
                }
                #pragma unroll
                for (int i = 0; i < 8; i++) {
                    bool g = mv[2*i+1] > mv[2*i];
                    mv[i] = g ? mv[2*i+1] : mv[2*i];
                    mi[i] = g ? mi[2*i+1] : mi[2*i];
                }
                #pragma unroll
                for (int i = 0; i < 4; i++) {
                    bool g = mv[2*i+1] > mv[2*i];
                    mv[i] = g ? mv[2*i+1] : mv[2*i];
                    mi[i] = g ? mi[2*i+1] : mi[2*i];
                }
                #pragma unroll
                for (int i = 0; i < 2; i++) {
                    bool g = mv[2*i+1] > mv[2*i];
                    mv[i] = g ? mv[2*i+1] : mv[2*i];
                    mi[i] = g ? mi[2*i+1] : mi[2*i];
                }
                bp[t * Ln + j] = (uint8_t)mi[0];
            }
        }
        __syncthreads();
    }

    // tail
    if (wv == 0) {
        // layout of final av depends on parity of last executed step
        int oT = ((slen - 1) & 1) ? o4 : o5;
        float mm = av; int ai = oT;
        #pragma unroll
        for (int off = 32; off >= 1; off >>= 1) {
            float om = __shfl_xor(mm, off);
            int   oi = __shfl_xor(ai, off);
            if (om > mm || (om == mm && oi < ai)) { mm = om; ai = oi; }
        }
        if (lane == 0) s_last = ai;
    } else if (wv == 1) {
        // 64-lane sum counts each state twice -> subtract 1 from log2
        float ss = a;
        #pragma unroll
        for (int off = 32; off >= 1; off >>= 1) ss += __shfl_xor(ss, off);
        if (lane == 0)
            wsf[LOGNORM_OFF + b] = (log2f(ss) - 1.0f + (float)Eacc) * LN2f;
    } else {
        int stripe = (wv - 2) * 2 + (lane >> 5);
        int cc = Tn / CH - 1;
        int pb = cc * CH;
        int pe = Tn; if (pe > slen) pe = slen;
        for (int t = pb + stripe; t < pe; t += 12) {
            const float* ar = al + (t - 1) * Ln;
            float vv[32];
            #pragma unroll
            for (int i = 0; i < 32; i += 4) {
                float4 a4 = *(const float4*)(ar + i);
                vv[i]     = a4.x + trH[i];
                vv[i + 1] = a4.y + trH[i + 1];
                vv[i + 2] = a4.z + trH[i + 2];
                vv[i + 3] = a4.w + trH[i + 3];
            }
            float mv[16]; int mi[16];
            #pragma unroll
            for (int i = 0; i < 16; i++) {
                bool g = vv[2*i+1] > vv[2*i];
                mv[i] = g ? vv[2*i+1] : vv[2*i];
                mi[i] = g ? (2*i+1) : (2*i);
            }
            #pragma unroll
            for (int i = 0; i < 8; i++) {
                bool g = mv[2*i+1] > mv[2*i];
                mv[i] = g ? mv[2*i+1] : mv[2*i];
                mi[i] = g ? mi[2*i+1] : mi[2*i];
            }
            #pragma unroll
            for (int i = 0; i < 4; i++) {
                bool g = mv[2*i+1] > mv[2*i];
                mv[i] = g ? mv[2*i+1] : mv[2*i];
                mi[i] = g ? mi[2*i+1] : mi[2*i];
            }
            #pragma unroll
            for (int i = 0; i < 2; i++) {
                bool g = mv[2*i+1] > mv[2*i];
                mv[i] = g ? mv[2*i+1] : mv[2*i];
                mi[i] = g ? mi[2*i+1] : mi[2*i];
            }
            bp[t * Ln + j] = (uint8_t)mi[0];
        }
    }
    __syncthreads();

    // ---------------- segmented parallel backtrace ----------------
    int sseg = tid >> 5, ent = tid & 31;
    {
        int y = ent;
        for (int p = 32 * sseg + 31; p >= 32 * sseg; p--) y = bp[p * Ln + y];
        Fm[sseg * 32 + ent] = (uint8_t)y;
    }
    __syncthreads();
    if (tid == 0) {
        int y = s_last;
        btag[15] = y;
        for (int ss = 15; ss >= 1; ss--) { y = Fm[ss * 32 + y]; btag[ss - 1] = y; }
    }
    __syncthreads();
    int q = tid;
    int y = btag[sseg];
    for (int p = 32 * sseg + 31; p >= q + 1; p--) y = bp[p * Ln + y];
    out[1 + (size_t)b * Tn + q] = (float)y;

    int lbl = label[(size_t)b * Tn + q];
    float tpf = (lbl > 0 && y == lbl) ? 1.f : 0.f;
    float tnf = (lbl > 0 && y != lbl) ? 1.f : 0.f;
    float fpf = (q < slen && lbl == 0 && y > 0) ? 1.f : 0.f;
    #pragma unroll
    for (int off = 32; off >= 1; off >>= 1) {
        tpf += __shfl_xor(tpf, off);
        tnf += __shfl_xor(tnf, off);
        fpf += __shfl_xor(fpf, off);
    }
    if (lane == 0) { credA[wv] = tpf; credB[wv] = tnf; credC[wv] = fpf; }
    __syncthreads();
    if (tid == 0) {
        float aa = 0.f, bb2 = 0.f, cc2 = 0.f;
        #pragma unroll
        for (int w = 0; w < 8; w++) { aa += credA[w]; bb2 += credB[w]; cc2 += credC[w]; }
        wsf[CNT_OFF + b] = aa;
        wsf[CNT_OFF + Bn + b] = bb2;
        wsf[CNT_OFF + 2 * Bn + b] = cc2;
    }
}

// ---------------------------------------------------------------------------
// Kernel 3: final scalar reductions
// ---------------------------------------------------------------------------
__global__ __launch_bounds__(64) void crf_final(const float* __restrict__ wsf,
                                                float* __restrict__ out)
{
    int lane = threadIdx.x;
    float nll = wsf[LOGNORM_OFF + lane] - wsf[SCORE_OFF + lane];
    float tp = wsf[CNT_OFF + lane];
    float tn = wsf[CNT_OFF + Bn + lane];
    float fp = wsf[CNT_OFF + 2 * Bn + lane];
    #pragma unroll
    for (int off = 32; off >= 1; off >>= 1) {
        nll += __shfl_xor(nll, off);
        tp  += __shfl_xor(tp, off);
        tn  += __shfl_xor(tn, off);
        fp  += __shfl_xor(fp, off);
    }
    if (lane == 0) {
        out[0] = nll * (1.f / 64.f);
        out[1 + Bn * Tn + 0] = tp;
        out[1 + Bn * Tn + 1] = tn;
        out[1 + Bn * Tn + 2] = fp;
    }
}

extern "C" void kernel_launch(void* const* d_in, const int* in_sizes, int n_in,
                              void* d_out, int out_size, void* d_ws, size_t ws_size,
                              hipStream_t stream) {
    const float* x     = (const float*)d_in[0];
    const float* W     = (const float*)d_in[1];
    const float* bias  = (const float*)d_in[2];
    const float* trans = (const float*)d_in[3];
    const int* label   = (const int*)d_in[4];
    const int* seqlen  = (const int*)d_in[5];
    float* out = (float*)d_out;
    float* wsf = (float*)d_ws;

    gemm_emis<<<dim3(Bn * (Tn / BM)), dim3(256), 0, stream>>>(x, W, bias, seqlen, wsf + EMIS_OFF);
    crf_forward<<<dim3(Bn), dim3(512), 0, stream>>>(wsf + EMIS_OFF, trans, label, seqlen, out, wsf);
    crf_final<<<dim3(1), dim3(64), 0, stream>>>(wsf, out);
}